// Round 7
// baseline (35511.224 us; speedup 1.0000x reference)
//
#include <hip/hip_runtime.h>

// ---------------------------------------------------------------------------
// Persistent seq2seq LSTM, v7: K-split GEMM with cached partials.
// 256 blocks x 1024 threads (16 waves: mt = w&7, kh = w>>3).
// Block b: g = b>>2 (n-group, units g*16..+16 -> 64 gate cols q*1024+g*16+u),
//          s = b&3  (k-slab: x k in [s*128,+128) + h k in [s*256,+256)).
// Per step: slab GEMM (split-bf16, 3 terms, 12 accs) -> cached C partial
// (64KB: [kh][64 col][128 row] fp32) -> release-wb + pflag -> group pwait(4)
// -> acquire-inv (THE one L2 inv per block/step; also freshens h/x/y reads)
// -> reduce 32 loads/thread + LSTM pointwise (c in regs) -> pack h (UC) ->
// hflag. Decoder adds v6's fc (blocks>=128, UC hp reads) and softmax+y-pack
// (blocks<128) chains via fflag/yflag.
// h/x/y payloads: UC (agent WT) writes + CACHED reads (fresh via the inv).
// C partials: cached writes + wbl2 release + cached reads after inv.
// Tightened waits: h-wait = slab range (64 flags) + group range (4 flags).
// ---------------------------------------------------------------------------

#define TS 384

typedef __attribute__((ext_vector_type(8))) short bf16x8;
typedef __attribute__((ext_vector_type(4))) float f32x4;

#define WS_XR 4096u
#define XR_SLOT 262144u                        // per slot: hi 128KB + lo 128KB
#define WS_HP (WS_XR + 4u*XR_SLOT)             // 1052672
#define HP_BUF 524288u                         // per buf: hi 256KB + lo 256KB
#define WS_C  (WS_HP + 2u*HP_BUF)              // 2101248; 256 x 64KB = 16MB
#define WS_FPN (WS_C + 16777216u)              // 18878464; fc partials 2MB
#define WS_TOTAL (WS_FPN + 2097152u)

#define MFMA __builtin_amdgcn_mfma_f32_16x16x32_bf16

__device__ __forceinline__ unsigned short bf16r(float v) {
  unsigned u = __float_as_uint(v);
  u += 0x7FFFu + ((u >> 16) & 1u);
  return (unsigned short)(u >> 16);
}
__device__ __forceinline__ float bf2f(unsigned short h) {
  return __uint_as_float(((unsigned)h) << 16);
}
__device__ __forceinline__ void split2(float v, short& hi, short& lo) {
  unsigned short h = bf16r(v);
  float r = v - bf2f(h);
  hi = (short)h; lo = (short)bf16r(r);
}
__device__ __forceinline__ float sigm(float v)  { return 1.0f / (1.0f + __expf(-v)); }
__device__ __forceinline__ float tanhfa(float v){ return 1.0f - 2.0f / (__expf(2.0f*v) + 1.0f); }

__device__ __forceinline__ void st_u64(void* p, unsigned long long v) {
  __hip_atomic_store((unsigned long long*)p, v, __ATOMIC_RELAXED, __HIP_MEMORY_SCOPE_AGENT);
}
__device__ __forceinline__ void st_f32(float* p, float v) {
  __hip_atomic_store(p, v, __ATOMIC_RELAXED, __HIP_MEMORY_SCOPE_AGENT);
}
__device__ __forceinline__ float ld_f32(const float* p) {
  return __hip_atomic_load(p, __ATOMIC_RELAXED, __HIP_MEMORY_SCOPE_AGENT);
}
union FRAG { unsigned long long q[2]; bf16x8 v; };
__device__ __forceinline__ bf16x8 ld_frag(const short* base) {
  FRAG u;
  u.q[0] = __hip_atomic_load((const unsigned long long*)base, __ATOMIC_RELAXED, __HIP_MEMORY_SCOPE_AGENT);
  u.q[1] = __hip_atomic_load((const unsigned long long*)(base + 4), __ATOMIC_RELAXED, __HIP_MEMORY_SCOPE_AGENT);
  return u.v;
}

// ---- sync primitives --------------------------------------------------------
__device__ __forceinline__ void setflag(unsigned* flag, unsigned val) {
  asm volatile("s_waitcnt vmcnt(0)" ::: "memory");
  __syncthreads();
  if (threadIdx.x == 0) {
    __hip_atomic_store(flag, val, __ATOMIC_RELAXED, __HIP_MEMORY_SCOPE_AGENT);
    asm volatile("s_waitcnt vmcnt(0)" ::: "memory");
  }
}
// release-wb (drains this block's cached C to LLC) then flag
__device__ __forceinline__ void release_set(unsigned* flag, unsigned val) {
  asm volatile("s_waitcnt vmcnt(0)" ::: "memory");
  __syncthreads();
  if (threadIdx.x == 0) {
    __builtin_amdgcn_fence(__ATOMIC_RELEASE, "agent");   // buffer_wbl2 + wait
    __hip_atomic_store(flag, val, __ATOMIC_RELAXED, __HIP_MEMORY_SCOPE_AGENT);
    asm volatile("s_waitcnt vmcnt(0)" ::: "memory");
  }
}
// wave-0-parallel poll of nflags (4 per lane)
__device__ __forceinline__ void waitflags(const unsigned* flags, int nflags,
                                          unsigned target, int* sDead) {
  if (threadIdx.x < 64) {
    const int i = threadIdx.x;
    const bool act = (i * 4) < nflags;
    const unsigned long long* q = (const unsigned long long*)(flags + i * 4);
    unsigned spins = 0;
    for (;;) {
      bool ok = true;
      if (act) {
        unsigned long long q0 = __hip_atomic_load(q, __ATOMIC_RELAXED, __HIP_MEMORY_SCOPE_AGENT);
        unsigned long long q1 = __hip_atomic_load(q + 1, __ATOMIC_RELAXED, __HIP_MEMORY_SCOPE_AGENT);
        ok = ((unsigned)q0 >= target) && ((unsigned)(q0 >> 32) >= target)
          && ((unsigned)q1 >= target) && ((unsigned)(q1 >> 32) >= target);
      }
      if (__all(ok)) break;
      __builtin_amdgcn_s_sleep(1);
      if (++spins > (1u << 19)) { if (i == 0) *sDead = 1; break; }
    }
  }
  __syncthreads();
}
// t0 polls 4 flags; optional acquire fence (L1+L2 inv) on success
__device__ __forceinline__ void wait4(const unsigned* f4, unsigned target,
                                      bool fence, int* sDead) {
  if (threadIdx.x == 0) {
    unsigned spins = 0;
    for (;;) {
      unsigned long long q0 = __hip_atomic_load((const unsigned long long*)f4,
                                 __ATOMIC_RELAXED, __HIP_MEMORY_SCOPE_AGENT);
      unsigned long long q1 = __hip_atomic_load((const unsigned long long*)(f4 + 2),
                                 __ATOMIC_RELAXED, __HIP_MEMORY_SCOPE_AGENT);
      if ((unsigned)q0 >= target && (unsigned)(q0 >> 32) >= target &&
          (unsigned)q1 >= target && (unsigned)(q1 >> 32) >= target) break;
      __builtin_amdgcn_s_sleep(1);
      if (++spins > (1u << 19)) { *sDead = 1; break; }
    }
    if (fence) __builtin_amdgcn_fence(__ATOMIC_ACQUIRE, "agent");
  }
  __syncthreads();
}

// ---- weight loaders --------------------------------------------------------
// LDS B layout: frag idx (nt*12 + kbl)*64 + l ; kbl 0..3 = x-slab kbs, 4..11 = h
__device__ void load_gw(const float* __restrict__ Wx, const float* __restrict__ Wh,
                        int g, int s, short* sBh, short* sBl) {
  for (int idx = threadIdx.x; idx < 24576; idx += 1024) {
    int j = idx & 7, l = (idx >> 3) & 63, chunk = idx >> 9;   // 0..47
    int nt = chunk / 12, kbl = chunk % 12;
    int gcol = nt * 1024 + g * 16 + (l & 15);
    int kin = ((l >> 4) << 3) + j;
    float wv;
    if (kbl < 4) wv = Wx[(size_t)(s * 128 + kbl * 32 + kin) * 4096 + gcol];
    else         wv = Wh[(size_t)(s * 256 + (kbl - 4) * 32 + kin) * 4096 + gcol];
    short hi, lo; split2(wv, hi, lo);
    sBh[idx] = hi; sBl[idx] = lo;
  }
}
__device__ void load_fcw(const float* __restrict__ fcW, int kg, int cg,
                         short* sFh, short* sFl) {
  for (int idx = threadIdx.x; idx < 4096; idx += 1024) {
    int j = idx & 7, l = (idx >> 3) & 63, kb = idx >> 9;
    int unit = kg * 256 + kb * 32 + ((l >> 4) << 3) + j;
    int col = cg * 16 + (l & 15);
    short hi, lo; split2(fcW[(size_t)unit * 512 + col], hi, lo);
    sFh[idx] = hi; sFl[idx] = lo;
  }
}

// ---- slab GEMM part: NKB kbs, 12 accs (4 nt x 3 terms), 1-ahead A prefetch -
template<int NKB>
__device__ __forceinline__ void gg_part(const short* AH_, const short* AL_,
    const short* sBh, const short* sBl, int mt, int l,
    int kbgA0, int kblB0, f32x4* acc)
{
  const bf16x8* AH = (const bf16x8*)AH_;
  const bf16x8* AL = (const bf16x8*)AL_;
  const bf16x8* BH = (const bf16x8*)sBh;
  const bf16x8* BL = (const bf16x8*)sBl;
  bf16x8 ah = AH[(kbgA0 * 8 + mt) * 64 + l];
  bf16x8 al = AL[(kbgA0 * 8 + mt) * 64 + l];
  #pragma unroll
  for (int i = 0; i < NKB; ++i) {
    bf16x8 ahn = ah, aln = al;
    if (i + 1 < NKB) {
      ahn = AH[((kbgA0 + i + 1) * 8 + mt) * 64 + l];
      aln = AL[((kbgA0 + i + 1) * 8 + mt) * 64 + l];
    }
    const int kbl = kblB0 + i;
    #pragma unroll
    for (int nt = 0; nt < 4; ++nt) {
      bf16x8 bh = BH[(nt * 12 + kbl) * 64 + l];
      bf16x8 bl = BL[(nt * 12 + kbl) * 64 + l];
      acc[nt * 3 + 0] = MFMA(ah, bh, acc[nt * 3 + 0], 0, 0, 0);
      acc[nt * 3 + 1] = MFMA(ah, bl, acc[nt * 3 + 1], 0, 0, 0);
      acc[nt * 3 + 2] = MFMA(al, bh, acc[nt * 3 + 2], 0, 0, 0);
    }
    ah = ahn; al = aln;
  }
}

// ---- x conversion into fragment-ordered ring slot (UC stores) --------------
__device__ __forceinline__ void conv_x(const float* __restrict__ xsrc,
                                       short* dstH, short* dstL, int b, int tl) {
  if (tl < 32) {
    int g = b * 32 + tl;                      // chunk 0..8191
    int l = g & 63, mt = (g >> 6) & 7, kb = g >> 9;
    int row = mt * 16 + (l & 15), k = kb * 32 + ((l >> 4) << 3);
    const float* xs = xsrc + (size_t)row * 512 + k;
    unsigned long long h64[2] = {0, 0}, l64[2] = {0, 0};
    #pragma unroll
    for (int j = 0; j < 8; ++j) {
      short hi, lo; split2(xs[j], hi, lo);
      h64[j >> 2] |= (unsigned long long)(unsigned short)hi << ((j & 3) * 16);
      l64[j >> 2] |= (unsigned long long)(unsigned short)lo << ((j & 3) * 16);
    }
    int off = g * 8;
    st_u64(dstH + off, h64[0]); st_u64(dstH + off + 4, h64[1]);
    st_u64(dstL + off, l64[0]); st_u64(dstL + off + 4, l64[1]);
  }
}

__global__ void __launch_bounds__(1024, 1)
lstm7(const float* __restrict__ x, const float* __restrict__ h0p,
      const float* __restrict__ c0p, const float* __restrict__ eWx,
      const float* __restrict__ eWh, const float* __restrict__ eb,
      const float* __restrict__ dWx, const float* __restrict__ dWh,
      const float* __restrict__ db, const float* __restrict__ fcW,
      const float* __restrict__ fcb, float* __restrict__ out,
      char* __restrict__ ws)
{
  __shared__ __align__(16) short sBh[24576], sBl[24576];   // 96 KB
  __shared__ __align__(16) short sFh[4096], sFl[4096];     // 16 KB
  __shared__ unsigned hsplit[512];
  __shared__ float ybuf[512];
  __shared__ float red[16];
  __shared__ int sDead;

  const int b = blockIdx.x, t = threadIdx.x;
  const int w = t >> 6, l = t & 63;
  const int mt = w & 7, kh = w >> 3;
  const int g = b >> 2, s = b & 3;
  if (t == 0) sDead = 0;

  unsigned* hflag = (unsigned*)ws;                 // 256
  unsigned* yflag = (unsigned*)(ws + 1024);        // 128
  unsigned* fflag = (unsigned*)(ws + 2048);        // 128
  unsigned* pflag = (unsigned*)(ws + 3072);        // 256

  short* xrH[4]; short* xrL[4];
  #pragma unroll
  for (int s4 = 0; s4 < 4; ++s4) {
    xrH[s4] = (short*)(ws + WS_XR + s4 * XR_SLOT);
    xrL[s4] = (short*)(ws + WS_XR + s4 * XR_SLOT + 131072u);
  }
  short* hpH[2]; short* hpL[2];
  #pragma unroll
  for (int b2 = 0; b2 < 2; ++b2) {
    hpH[b2] = (short*)(ws + WS_HP + b2 * HP_BUF);
    hpL[b2] = (short*)(ws + WS_HP + b2 * HP_BUF + 262144u);
  }
  float* Call = (float*)(ws + WS_C);
  float* Cb   = Call + (size_t)b * 16384 + kh * 8192;   // my write plane
  const float* Cg = Call + (size_t)(g * 4) * 16384;     // group read base
  float* fp = (float*)(ws + WS_FPN);

  const int u_pw = t >> 5, rl_pw = t & 31;               // pointwise cell (t<512)

  // ================= init =================
  load_gw(eWx, eWh, g, s, sBh, sBl);
  conv_x(x, xrH[0], xrL[0], b, t);                       // x(0)
  conv_x(x + 65536, xrH[1], xrL[1], b, t);               // x(1)
  if (t < 64) {                                          // h0 -> hp[0]
    int hg = b * 64 + t;
    int ll = hg & 63, mtt = (hg >> 6) & 7, hk = hg >> 9;
    int row = mtt * 16 + (ll & 15), k = hk * 32 + ((ll >> 4) << 3);
    const float* hs = h0p + (size_t)row * 1024 + k;
    unsigned long long h64[2] = {0, 0}, l64[2] = {0, 0};
    #pragma unroll
    for (int j = 0; j < 8; ++j) {
      short hi, lo; split2(hs[j], hi, lo);
      h64[j >> 2] |= (unsigned long long)(unsigned short)hi << ((j & 3) * 16);
      l64[j >> 2] |= (unsigned long long)(unsigned short)lo << ((j & 3) * 16);
    }
    int off = hg * 8;
    st_u64(hpH[0] + off, h64[0]); st_u64(hpH[0] + off + 4, h64[1]);
    st_u64(hpL[0] + off, l64[0]); st_u64(hpL[0] + off + 4, l64[1]);
  }
  float creg = 0.f, bq0 = 0.f, bq1 = 0.f, bq2 = 0.f, bq3 = 0.f;
  if (t < 512) {
    int row = s * 32 + rl_pw, ug = g * 16 + u_pw;
    creg = c0p[(size_t)row * 1024 + ug];
    bq0 = eb[0 * 1024 + ug]; bq1 = eb[1 * 1024 + ug];
    bq2 = eb[2 * 1024 + ug]; bq3 = eb[3 * 1024 + ug];
  }
  setflag(&hflag[b], 1u);
  waitflags(hflag, 256, 1u, &sDead);                     // init barrier
  if (t == 0) __builtin_amdgcn_fence(__ATOMIC_ACQUIRE, "agent");
  __syncthreads();
  if (sDead) return;

  // ================= encoder =================
  // step st: waits hflag>=st+1, pflag st+1, sets hflag st+2
  for (int st = 0; st < TS; ++st) {
    const int rb = st & 1, wb = rb ^ 1;
    f32x4 z = {0.f, 0.f, 0.f, 0.f};
    f32x4 acc[12] = {z, z, z, z, z, z, z, z, z, z, z, z};
    // x-part before the wait (freshness via prev step's inv; WAR via flag web)
    gg_part<2>(xrH[st & 3], xrL[st & 3], sBh, sBl, mt, l, s * 4 + kh * 2, kh * 2, acc);
    waitflags(hflag + s * 64, 64, (unsigned)(st + 1), &sDead);   // h producers for my slab
    if (sDead) return;
    gg_part<4>(hpH[rb], hpL[rb], sBh, sBl, mt, l, s * 8 + kh * 4, 4 + kh * 4, acc);
    if ((g >> 4) != s) {                                  // C-WAR: my group's readers done
      wait4(hflag + g * 4, (unsigned)(st + 1), false, &sDead);
      if (sDead) return;
    }
    // store C partial (cached)
    #pragma unroll
    for (int nt = 0; nt < 4; ++nt) {
      f32x4 sv = acc[nt * 3] + (acc[nt * 3 + 1] + acc[nt * 3 + 2]);
      *(f32x4*)&Cb[(nt * 16 + (l & 15)) * 128 + mt * 16 + ((l >> 4) << 2)] = sv;
    }
    release_set(&pflag[b], (unsigned)(st + 1));           // wbl2 + pflag
    wait4(pflag + g * 4, (unsigned)(st + 1), true, &sDead); // + THE inv
    if (sDead) return;
    if (t < 512) {                                        // reduce + pointwise
      int row = s * 32 + rl_pw;
      float g0 = bq0, g1 = bq1, g2 = bq2, g3 = bq3;
      #pragma unroll
      for (int sl = 0; sl < 4; ++sl)
        #pragma unroll
        for (int kp = 0; kp < 2; ++kp) {
          const float* Cp = Cg + sl * 16384 + kp * 8192 + row;
          g0 += Cp[(0 * 16 + u_pw) * 128];
          g1 += Cp[(1 * 16 + u_pw) * 128];
          g2 += Cp[(2 * 16 + u_pw) * 128];
          g3 += Cp[(3 * 16 + u_pw) * 128];
        }
      creg = sigm(g1) * creg + sigm(g0) * tanhfa(g2);
      float h = sigm(g3) * tanhfa(creg);
      short hi, lo; split2(h, hi, lo);
      hsplit[u_pw * 32 + rl_pw] = ((unsigned)(unsigned short)hi << 16) | (unsigned short)lo;
    } else if (st + 2 < TS) {
      conv_x(x + (size_t)(st + 2) * 65536, xrH[(st + 2) & 3], xrL[(st + 2) & 3], b, t - 512);
    }
    __syncthreads();
    if (t < 64) {                                         // pack h (UC)
      int rl = t >> 1, seg = t & 1;
      int row = s * 32 + rl;
      int k0 = g * 16 + seg * 8;
      int kbg = k0 >> 5, kseg = (k0 >> 3) & 3;
      int lane_ = (kseg << 4) | (row & 15);
      int off = ((kbg * 8 + (row >> 4)) * 64 + lane_) * 8;
      unsigned long long h64[2] = {0, 0}, l64[2] = {0, 0};
      #pragma unroll
      for (int j = 0; j < 8; ++j) {
        unsigned v = hsplit[(seg * 8 + j) * 32 + rl];
        h64[j >> 2] |= (unsigned long long)(v >> 16) << ((j & 3) * 16);
        l64[j >> 2] |= (unsigned long long)(v & 0xFFFFu) << ((j & 3) * 16);
      }
      st_u64(hpH[wb] + off, h64[0]); st_u64(hpH[wb] + off + 4, h64[1]);
      st_u64(hpL[wb] + off, l64[0]); st_u64(hpL[wb] + off + 4, l64[1]);
    }
    setflag(&hflag[b], (unsigned)(st + 2));
  }

  // ================= switch to decoder =================
  load_gw(dWx, dWh, g, s, sBh, sBl);
  if (b >= 128) load_fcw(fcW, (b - 128) >> 5, (b - 128) & 31, sFh, sFl);
  if (t < 32) {                                           // zero y0 (slot 0)
    int off = (b * 32 + t) * 8;
    st_u64(xrH[0] + off, 0ull); st_u64(xrH[0] + off + 4, 0ull);
    st_u64(xrL[0] + off, 0ull); st_u64(xrL[0] + off + 4, 0ull);
  }
  creg = 0.0f;
  if (t < 512) {
    int ug = g * 16 + u_pw;
    bq0 = db[0 * 1024 + ug]; bq1 = db[1 * 1024 + ug];
    bq2 = db[2 * 1024 + ug]; bq3 = db[3 * 1024 + ug];
  }
  float fcb_r = (t < 512) ? fcb[t] : 0.f;
  setflag(&hflag[b], (unsigned)(TS + 2));

  // ================= decoder =================
  const unsigned DB = (unsigned)(TS + 2);
  for (int st = 0; st < TS; ++st) {
    const int rb = st & 1, wb = rb ^ 1;
    f32x4 z = {0.f, 0.f, 0.f, 0.f};
    f32x4 acc[12] = {z, z, z, z, z, z, z, z, z, z, z, z};
    waitflags(hflag + s * 64, 64, DB + (unsigned)st, &sDead);
    if (sDead) return;
    gg_part<4>(hpH[rb], hpL[rb], sBh, sBl, mt, l, s * 8 + kh * 4, 4 + kh * 4, acc);
    waitflags(yflag, 128, (unsigned)st, &sDead);          // y(st-1)
    if (sDead) return;
    gg_part<2>(xrH[st & 1], xrL[st & 1], sBh, sBl, mt, l, s * 4 + kh * 2, kh * 2, acc);
    if ((g >> 4) != s) {
      wait4(hflag + g * 4, DB + (unsigned)st, false, &sDead);
      if (sDead) return;
    }
    #pragma unroll
    for (int nt = 0; nt < 4; ++nt) {
      f32x4 sv = acc[nt * 3] + (acc[nt * 3 + 1] + acc[nt * 3 + 2]);
      *(f32x4*)&Cb[(nt * 16 + (l & 15)) * 128 + mt * 16 + ((l >> 4) << 2)] = sv;
    }
    release_set(&pflag[b], (unsigned)(TS + st + 1));
    wait4(pflag + g * 4, (unsigned)(TS + st + 1), true, &sDead);
    if (sDead) return;
    if (t < 512) {
      int row = s * 32 + rl_pw;
      float g0 = bq0, g1 = bq1, g2 = bq2, g3 = bq3;
      #pragma unroll
      for (int sl = 0; sl < 4; ++sl)
        #pragma unroll
        for (int kp = 0; kp < 2; ++kp) {
          const float* Cp = Cg + sl * 16384 + kp * 8192 + row;
          g0 += Cp[(0 * 16 + u_pw) * 128];
          g1 += Cp[(1 * 16 + u_pw) * 128];
          g2 += Cp[(2 * 16 + u_pw) * 128];
          g3 += Cp[(3 * 16 + u_pw) * 128];
        }
      creg = sigm(g1) * creg + sigm(g0) * tanhfa(g2);
      float h = sigm(g3) * tanhfa(creg);
      short hi, lo; split2(h, hi, lo);
      hsplit[u_pw * 32 + rl_pw] = ((unsigned)(unsigned short)hi << 16) | (unsigned short)lo;
    }
    __syncthreads();
    if (t < 64) {
      int rl = t >> 1, seg = t & 1;
      int row = s * 32 + rl;
      int k0 = g * 16 + seg * 8;
      int kbg = k0 >> 5, kseg = (k0 >> 3) & 3;
      int lane_ = (kseg << 4) | (row & 15);
      int off = ((kbg * 8 + (row >> 4)) * 64 + lane_) * 8;
      unsigned long long h64[2] = {0, 0}, l64[2] = {0, 0};
      #pragma unroll
      for (int j = 0; j < 8; ++j) {
        unsigned v = hsplit[(seg * 8 + j) * 32 + rl];
        h64[j >> 2] |= (unsigned long long)(v >> 16) << ((j & 3) * 16);
        l64[j >> 2] |= (unsigned long long)(v & 0xFFFFu) << ((j & 3) * 16);
      }
      st_u64(hpH[wb] + off, h64[0]); st_u64(hpH[wb] + off + 4, h64[1]);
      st_u64(hpL[wb] + off, l64[0]); st_u64(hpL[wb] + off + 4, l64[1]);
    }
    setflag(&hflag[b], DB + (unsigned)(st + 1));

    if (b >= 128) {
      // ---- fc GEMM (UC hp reads; no fence needed) ----
      const int f = b - 128, kg = f >> 5, cg = f & 31;
      waitflags(hflag + kg * 64, 64, DB + (unsigned)(st + 1), &sDead);
      if (sDead) return;
      {
        const bf16x8* FB = (const bf16x8*)sFh;
        const bf16x8* FL = (const bf16x8*)sFl;
        f32x4 a0 = z, a1 = z, a2 = z;
        #pragma unroll
        for (int kb = 0; kb < 4; ++kb) {
          int gkb = kg * 8 + kh * 4 + kb;
          bf16x8 ah = ld_frag(hpH[wb] + ((gkb * 8 + mt) * 64 + l) * 8);
          bf16x8 al = ld_frag(hpL[wb] + ((gkb * 8 + mt) * 64 + l) * 8);
          bf16x8 bh = FB[(kh * 4 + kb) * 64 + l];
          bf16x8 bl = FL[(kh * 4 + kb) * 64 + l];
          a0 = MFMA(ah, bh, a0, 0, 0, 0);
          a1 = MFMA(ah, bl, a1, 0, 0, 0);
          a2 = MFMA(al, bh, a2, 0, 0, 0);
        }
        f32x4 sv = a0 + (a1 + a2);
        int slice = kg * 2 + kh;
        int col = cg * 16 + (l & 15), r0 = mt * 16 + ((l >> 4) << 2);
        #pragma unroll
        for (int j = 0; j < 4; ++j)
          st_f32(&fp[(size_t)(slice * 128 + r0 + j) * 512 + col], sv[j]);
      }
      setflag(&fflag[f], (unsigned)(st + 1));
    } else {
      // ---- softmax + y-pack (UC fp reads) ----
      waitflags(fflag, 128, (unsigned)(st + 1), &sDead);
      if (sDead) return;
      float v = 0.f, e = 0.f, mx;
      if (t < 512) {
        v = fcb_r;
        #pragma unroll
        for (int s8 = 0; s8 < 8; ++s8)
          v += ld_f32(&fp[(size_t)(s8 * 128 + b) * 512 + t]);
        mx = v;
        #pragma unroll
        for (int o = 32; o > 0; o >>= 1) mx = fmaxf(mx, __shfl_xor(mx, o));
        if (l == 0) red[w] = mx;
      }
      __syncthreads();
      if (t < 512) {
        mx = red[0];
        #pragma unroll
        for (int i = 1; i < 8; ++i) mx = fmaxf(mx, red[i]);
        e = __expf(v - mx);
        float ss = e;
        #pragma unroll
        for (int o = 32; o > 0; o >>= 1) ss += __shfl_xor(ss, o);
        if (l == 0) red[8 + w] = ss;
      }
      __syncthreads();
      if (t < 512) {
        float ss = (red[8] + red[9]) + (red[10] + red[11])
                 + (red[12] + red[13]) + (red[14] + red[15]);
        float y = e / ss;
        out[((size_t)st * 128 + b) * 512 + t] = y;
        ybuf[t] = y;
      }
      __syncthreads();
      if (t < 64) {                                       // pack y row b
        int kb = t >> 2, seg = t & 3;
        int k = kb * 32 + seg * 8;
        int lane_ = (seg << 4) | (b & 15), mtt = b >> 4;
        int off = ((kb * 8 + mtt) * 64 + lane_) * 8;
        int yw = (st & 1) ^ 1;
        unsigned long long h64[2] = {0, 0}, l64[2] = {0, 0};
        #pragma unroll
        for (int j = 0; j < 8; ++j) {
          short hi, lo; split2(ybuf[k + j], hi, lo);
          h64[j >> 2] |= (unsigned long long)(unsigned short)hi << ((j & 3) * 16);
          l64[j >> 2] |= (unsigned long long)(unsigned short)lo << ((j & 3) * 16);
        }
        st_u64(xrH[yw] + off, h64[0]); st_u64(xrH[yw] + off + 4, h64[1]);
        st_u64(xrL[yw] + off, l64[0]); st_u64(xrL[yw] + off + 4, l64[1]);
      }
      setflag(&yflag[b], (unsigned)(st + 1));
    }
  }
}

extern "C" void kernel_launch(void* const* d_in, const int* in_sizes, int n_in,
                              void* d_out, int out_size, void* d_ws, size_t ws_size,
                              hipStream_t stream) {
  const float* x   = (const float*)d_in[0];
  const float* h0  = (const float*)d_in[1];
  const float* c0  = (const float*)d_in[2];
  const float* eWx = (const float*)d_in[3];
  const float* eWh = (const float*)d_in[4];
  const float* eb  = (const float*)d_in[5];
  const float* dWx = (const float*)d_in[6];
  const float* dWh = (const float*)d_in[7];
  const float* db  = (const float*)d_in[8];
  const float* fcW = (const float*)d_in[9];
  const float* fcb = (const float*)d_in[10];
  float* out = (float*)d_out;

  if (ws_size < (size_t)WS_TOTAL) {
    hipMemsetAsync(d_out, 0xFF, (size_t)out_size * sizeof(float), stream);
    return;
  }
  hipMemsetAsync(d_ws, 0, 4096, stream);   // flag arrays
  hipLaunchKernelGGL(lstm7, dim3(256), dim3(1024), 0, stream,
                     x, h0, c0, eWx, eWh, eb, dWx, dWh, db, fcW, fcb, out,
                     (char*)d_ws);
}

// Round 8
// 18349.445 us; speedup vs baseline: 1.9353x; 1.9353x over previous
//
#include <hip/hip_runtime.h>

// ---------------------------------------------------------------------------
// Persistent seq2seq LSTM, v8: K-split + UC C-exchange, NO release fences.
// 256 blocks x 1024 threads (16 waves: mt=w&7, kh=w>>3).
// Block b: g=b>>2 (16 units: gate cols q*1024+g*16+u), s=b&3 (slab: x k in
// [s*128,+128), h k in [s*256,+256)). Weights for the slab in LDS (96KB).
// Per step: slab GEMM (split-bf16, 12 accs) -> kh=1 waves stage partial in
// LDS (32KB) -> kh=0 waves combine -> UC store C cell-major (32KB/block,
// float4 per (row,unit) = 4 gates) -> pflag -> pwait(4 flags)+acquire-inv
// (THE one inv/block/step; freshens cached hp/x reads) -> reduce: 1 cell/
// thread, 4 slabs x 2 u64 UC loads -> LSTM pointwise (c in regs) -> pack h
// (UC) -> hflag. Decoder adds fc (b>=128, UC hp reads) and softmax+y-pack
// (b<128) via fflag/yflag, same as v7.
// Coherence recipe: UC(agent) for all cross-block written payloads that are
// read UC (C, fp); UC-write + CACHED-read + per-step-inv for hp/x/y (bulk
// operands, L2-shared). No wbl2 anywhere (v7's 2.3x regression).
// ---------------------------------------------------------------------------

#define TS 384

typedef __attribute__((ext_vector_type(8))) short bf16x8;
typedef __attribute__((ext_vector_type(4))) float f32x4;

#define WS_XR 4096u
#define XR_SLOT 262144u                        // per slot: hi 128KB + lo 128KB
#define WS_HP (WS_XR + 4u*XR_SLOT)             // 1052672
#define HP_BUF 524288u                         // per buf: hi 256KB + lo 256KB
#define WS_C  (WS_HP + 2u*HP_BUF)              // 2101248; 256 x 32KB = 8MB
#define WS_FPN (WS_C + 8388608u)               // 10489856; fc partials 2MB
#define WS_TOTAL (WS_FPN + 2097152u)           // 12586 KB

#define MFMA __builtin_amdgcn_mfma_f32_16x16x32_bf16

__device__ __forceinline__ unsigned short bf16r(float v) {
  unsigned u = __float_as_uint(v);
  u += 0x7FFFu + ((u >> 16) & 1u);
  return (unsigned short)(u >> 16);
}
__device__ __forceinline__ float bf2f(unsigned short h) {
  return __uint_as_float(((unsigned)h) << 16);
}
__device__ __forceinline__ void split2(float v, short& hi, short& lo) {
  unsigned short h = bf16r(v);
  float r = v - bf2f(h);
  hi = (short)h; lo = (short)bf16r(r);
}
__device__ __forceinline__ float sigm(float v)  { return 1.0f / (1.0f + __expf(-v)); }
__device__ __forceinline__ float tanhfa(float v){ return 1.0f - 2.0f / (__expf(2.0f*v) + 1.0f); }

__device__ __forceinline__ void st_u64(void* p, unsigned long long v) {
  __hip_atomic_store((unsigned long long*)p, v, __ATOMIC_RELAXED, __HIP_MEMORY_SCOPE_AGENT);
}
__device__ __forceinline__ unsigned long long ld_u64(const void* p) {
  return __hip_atomic_load((const unsigned long long*)p, __ATOMIC_RELAXED, __HIP_MEMORY_SCOPE_AGENT);
}
__device__ __forceinline__ void st_f32(float* p, float v) {
  __hip_atomic_store(p, v, __ATOMIC_RELAXED, __HIP_MEMORY_SCOPE_AGENT);
}
__device__ __forceinline__ float ld_f32(const float* p) {
  return __hip_atomic_load(p, __ATOMIC_RELAXED, __HIP_MEMORY_SCOPE_AGENT);
}
union FRAG { unsigned long long q[2]; bf16x8 v; };
__device__ __forceinline__ bf16x8 ld_frag(const short* base) {
  FRAG u;
  u.q[0] = ld_u64(base);
  u.q[1] = ld_u64(base + 4);
  return u.v;
}

// ---- sync primitives --------------------------------------------------------
__device__ __forceinline__ void setflag(unsigned* flag, unsigned val) {
  asm volatile("s_waitcnt vmcnt(0)" ::: "memory");
  __syncthreads();
  if (threadIdx.x == 0) {
    __hip_atomic_store(flag, val, __ATOMIC_RELAXED, __HIP_MEMORY_SCOPE_AGENT);
    asm volatile("s_waitcnt vmcnt(0)" ::: "memory");
  }
}
// wave-0-parallel poll of nflags (4 per lane)
__device__ __forceinline__ void waitflags(const unsigned* flags, int nflags,
                                          unsigned target, int* sDead) {
  if (threadIdx.x < 64) {
    const int i = threadIdx.x;
    const bool act = (i * 4) < nflags;
    const unsigned long long* q = (const unsigned long long*)(flags + i * 4);
    unsigned spins = 0;
    for (;;) {
      bool ok = true;
      if (act) {
        unsigned long long q0 = ld_u64(q);
        unsigned long long q1 = ld_u64(q + 1);
        ok = ((unsigned)q0 >= target) && ((unsigned)(q0 >> 32) >= target)
          && ((unsigned)q1 >= target) && ((unsigned)(q1 >> 32) >= target);
      }
      if (__all(ok)) break;
      __builtin_amdgcn_s_sleep(1);
      if (++spins > (1u << 19)) { if (i == 0) *sDead = 1; break; }
    }
  }
  __syncthreads();
}
// t0 polls 4 flags; optional acquire fence (L1+L2 inv, NO writeback) on success
__device__ __forceinline__ void wait4(const unsigned* f4, unsigned target,
                                      bool fence, int* sDead) {
  if (threadIdx.x == 0) {
    unsigned spins = 0;
    for (;;) {
      unsigned long long q0 = ld_u64(f4);
      unsigned long long q1 = ld_u64(f4 + 2);
      if ((unsigned)q0 >= target && (unsigned)(q0 >> 32) >= target &&
          (unsigned)q1 >= target && (unsigned)(q1 >> 32) >= target) break;
      __builtin_amdgcn_s_sleep(1);
      if (++spins > (1u << 19)) { *sDead = 1; break; }
    }
    if (fence) __builtin_amdgcn_fence(__ATOMIC_ACQUIRE, "agent");
  }
  __syncthreads();
}

// ---- weight loaders --------------------------------------------------------
// LDS B layout: frag idx (nt*12 + kbl)*64 + l ; kbl 0..3 = x kbs, 4..11 = h kbs
__device__ void load_gw(const float* __restrict__ Wx, const float* __restrict__ Wh,
                        int g, int s, short* sBh, short* sBl) {
  for (int idx = threadIdx.x; idx < 24576; idx += 1024) {
    int j = idx & 7, l = (idx >> 3) & 63, chunk = idx >> 9;   // 0..47
    int nt = chunk / 12, kbl = chunk % 12;
    int gcol = nt * 1024 + g * 16 + (l & 15);
    int kin = ((l >> 4) << 3) + j;
    float wv;
    if (kbl < 4) wv = Wx[(size_t)(s * 128 + kbl * 32 + kin) * 4096 + gcol];
    else         wv = Wh[(size_t)(s * 256 + (kbl - 4) * 32 + kin) * 4096 + gcol];
    short hi, lo; split2(wv, hi, lo);
    sBh[idx] = hi; sBl[idx] = lo;
  }
}
__device__ void load_fcw(const float* __restrict__ fcW, int kg, int cg,
                         short* sFh, short* sFl) {
  for (int idx = threadIdx.x; idx < 4096; idx += 1024) {
    int j = idx & 7, l = (idx >> 3) & 63, kb = idx >> 9;
    int unit = kg * 256 + kb * 32 + ((l >> 4) << 3) + j;
    int col = cg * 16 + (l & 15);
    short hi, lo; split2(fcW[(size_t)unit * 512 + col], hi, lo);
    sFh[idx] = hi; sFl[idx] = lo;
  }
}

// ---- slab GEMM part: NKB kbs, 12 accs (4 gates x 3 terms), 1-ahead A pref --
template<int NKB>
__device__ __forceinline__ void gg_part(const short* AH_, const short* AL_,
    const short* sBh, const short* sBl, int mt, int l,
    int kbgA0, int kblB0, f32x4* acc)
{
  const bf16x8* AH = (const bf16x8*)AH_;
  const bf16x8* AL = (const bf16x8*)AL_;
  const bf16x8* BH = (const bf16x8*)sBh;
  const bf16x8* BL = (const bf16x8*)sBl;
  bf16x8 ah = AH[(kbgA0 * 8 + mt) * 64 + l];
  bf16x8 al = AL[(kbgA0 * 8 + mt) * 64 + l];
  #pragma unroll
  for (int i = 0; i < NKB; ++i) {
    bf16x8 ahn = ah, aln = al;
    if (i + 1 < NKB) {
      ahn = AH[((kbgA0 + i + 1) * 8 + mt) * 64 + l];
      aln = AL[((kbgA0 + i + 1) * 8 + mt) * 64 + l];
    }
    const int kbl = kblB0 + i;
    #pragma unroll
    for (int nt = 0; nt < 4; ++nt) {
      bf16x8 bh = BH[(nt * 12 + kbl) * 64 + l];
      bf16x8 bl = BL[(nt * 12 + kbl) * 64 + l];
      acc[nt * 3 + 0] = MFMA(ah, bh, acc[nt * 3 + 0], 0, 0, 0);
      acc[nt * 3 + 1] = MFMA(ah, bl, acc[nt * 3 + 1], 0, 0, 0);
      acc[nt * 3 + 2] = MFMA(al, bh, acc[nt * 3 + 2], 0, 0, 0);
    }
    ah = ahn; al = aln;
  }
}

// ---- x conversion into fragment-ordered ring slot (UC stores) --------------
__device__ __forceinline__ void conv_x(const float* __restrict__ xsrc,
                                       short* dstH, short* dstL, int b, int tl) {
  if (tl < 32) {
    int gch = b * 32 + tl;                    // chunk 0..8191
    int l = gch & 63, mt = (gch >> 6) & 7, kb = gch >> 9;
    int row = mt * 16 + (l & 15), k = kb * 32 + ((l >> 4) << 3);
    const float* xs = xsrc + (size_t)row * 512 + k;
    unsigned long long h64[2] = {0, 0}, l64[2] = {0, 0};
    #pragma unroll
    for (int j = 0; j < 8; ++j) {
      short hi, lo; split2(xs[j], hi, lo);
      h64[j >> 2] |= (unsigned long long)(unsigned short)hi << ((j & 3) * 16);
      l64[j >> 2] |= (unsigned long long)(unsigned short)lo << ((j & 3) * 16);
    }
    int off = gch * 8;
    st_u64(dstH + off, h64[0]); st_u64(dstH + off + 4, h64[1]);
    st_u64(dstL + off, l64[0]); st_u64(dstL + off + 4, l64[1]);
  }
}

__global__ void __launch_bounds__(1024, 1)
lstm8(const float* __restrict__ x, const float* __restrict__ h0p,
      const float* __restrict__ c0p, const float* __restrict__ eWx,
      const float* __restrict__ eWh, const float* __restrict__ eb,
      const float* __restrict__ dWx, const float* __restrict__ dWh,
      const float* __restrict__ db, const float* __restrict__ fcW,
      const float* __restrict__ fcb, float* __restrict__ out,
      char* __restrict__ ws)
{
  __shared__ __align__(16) short sBh[24576], sBl[24576];   // 96 KB
  __shared__ __align__(16) short sFh[4096], sFl[4096];     // 16 KB
  __shared__ __align__(16) float cstage[8192];             // 32 KB (kh=1 relay)
  __shared__ unsigned hsplit[512];
  __shared__ float ybuf[512];
  __shared__ float red[16];
  __shared__ int sDead;

  const int b = blockIdx.x, t = threadIdx.x;
  const int w = t >> 6, l = t & 63;
  const int mt = w & 7, kh = w >> 3;
  const int g = b >> 2, s = b & 3;
  if (t == 0) sDead = 0;

  unsigned* hflag = (unsigned*)ws;                 // 256
  unsigned* yflag = (unsigned*)(ws + 1024);        // 128
  unsigned* fflag = (unsigned*)(ws + 2048);        // 128
  unsigned* pflag = (unsigned*)(ws + 3072);        // 256

  short* xrH[4]; short* xrL[4];
  #pragma unroll
  for (int s4 = 0; s4 < 4; ++s4) {
    xrH[s4] = (short*)(ws + WS_XR + s4 * XR_SLOT);
    xrL[s4] = (short*)(ws + WS_XR + s4 * XR_SLOT + 131072u);
  }
  short* hpH[2]; short* hpL[2];
  #pragma unroll
  for (int b2 = 0; b2 < 2; ++b2) {
    hpH[b2] = (short*)(ws + WS_HP + b2 * HP_BUF);
    hpL[b2] = (short*)(ws + WS_HP + b2 * HP_BUF + 262144u);
  }
  float* Call = (float*)(ws + WS_C);               // 256 x 8192 floats
  float* Cb   = Call + (size_t)b * 8192;
  float* fp   = (float*)(ws + WS_FPN);

  const int rl_r = t >> 4, un_r = t & 15;          // reducer cell (t<512)

  // ================= init =================
  load_gw(eWx, eWh, g, s, sBh, sBl);
  conv_x(x, xrH[0], xrL[0], b, t);                       // x(0)
  conv_x(x + 65536, xrH[1], xrL[1], b, t);               // x(1)
  if (t < 64) {                                          // h0 -> hp[0]
    int hg = b * 64 + t;
    int ll = hg & 63, mtt = (hg >> 6) & 7, hk = hg >> 9;
    int row = mtt * 16 + (ll & 15), k = hk * 32 + ((ll >> 4) << 3);
    const float* hs = h0p + (size_t)row * 1024 + k;
    unsigned long long h64[2] = {0, 0}, l64[2] = {0, 0};
    #pragma unroll
    for (int j = 0; j < 8; ++j) {
      short hi, lo; split2(hs[j], hi, lo);
      h64[j >> 2] |= (unsigned long long)(unsigned short)hi << ((j & 3) * 16);
      l64[j >> 2] |= (unsigned long long)(unsigned short)lo << ((j & 3) * 16);
    }
    int off = hg * 8;
    st_u64(hpH[0] + off, h64[0]); st_u64(hpH[0] + off + 4, h64[1]);
    st_u64(hpL[0] + off, l64[0]); st_u64(hpL[0] + off + 4, l64[1]);
  }
  float creg = 0.f, bq0 = 0.f, bq1 = 0.f, bq2 = 0.f, bq3 = 0.f;
  if (t < 512) {
    int row = s * 32 + rl_r, ug = g * 16 + un_r;
    creg = c0p[(size_t)row * 1024 + ug];
    bq0 = eb[0 * 1024 + ug]; bq1 = eb[1 * 1024 + ug];
    bq2 = eb[2 * 1024 + ug]; bq3 = eb[3 * 1024 + ug];
  }
  setflag(&hflag[b], 1u);
  waitflags(hflag, 256, 1u, &sDead);                     // init barrier
  if (t == 0) __builtin_amdgcn_fence(__ATOMIC_ACQUIRE, "agent");
  __syncthreads();
  if (sDead) return;

  // ================= the per-step GEMM->C->reduce macro-flow =================
  // (written twice, enc/dec, due to differing operand sources)

  // ================= encoder =================
  for (int st = 0; st < TS; ++st) {
    const int rb = st & 1, wb = rb ^ 1;
    f32x4 z = {0.f, 0.f, 0.f, 0.f};
    f32x4 acc[12] = {z, z, z, z, z, z, z, z, z, z, z, z};
    // x-part before the h-wait
    gg_part<2>(xrH[st & 3], xrL[st & 3], sBh, sBl, mt, l, s * 4 + kh * 2, kh * 2, acc);
    waitflags(hflag + s * 64, 64, (unsigned)(st + 1), &sDead);   // slab h producers
    if (sDead) return;
    gg_part<4>(hpH[rb], hpL[rb], sBh, sBl, mt, l, s * 8 + kh * 4, 4 + kh * 4, acc);
    // C-WAR: group readers of step st-1 done
    wait4(hflag + g * 4, (unsigned)(st + 1), false, &sDead);
    if (sDead) return;
    // combine kh halves via LDS, UC-store C cells
    {
      f32x4 sv[4];
      #pragma unroll
      for (int nt = 0; nt < 4; ++nt)
        sv[nt] = acc[nt * 3] + (acc[nt * 3 + 1] + acc[nt * 3 + 2]);
      if (kh == 1) {
        #pragma unroll
        for (int j = 0; j < 4; ++j) {
          int cell = (mt * 16 + ((l >> 4) << 2) + j) * 16 + (l & 15);
          float4 val = make_float4(sv[0][j], sv[1][j], sv[2][j], sv[3][j]);
          *(float4*)&cstage[cell * 4] = val;
        }
      }
      __syncthreads();
      if (kh == 0) {
        #pragma unroll
        for (int j = 0; j < 4; ++j) {
          int cell = (mt * 16 + ((l >> 4) << 2) + j) * 16 + (l & 15);
          float4 o = *(const float4*)&cstage[cell * 4];
          union { float f[4]; unsigned long long q[2]; } uv;
          uv.f[0] = sv[0][j] + o.x; uv.f[1] = sv[1][j] + o.y;
          uv.f[2] = sv[2][j] + o.z; uv.f[3] = sv[3][j] + o.w;
          st_u64(Cb + cell * 4, uv.q[0]);
          st_u64(Cb + cell * 4 + 2, uv.q[1]);
        }
      }
    }
    setflag(&pflag[b], (unsigned)(st + 1));
    wait4(pflag + g * 4, (unsigned)(st + 1), true, &sDead);      // + THE inv
    if (sDead) return;
    if (t < 512) {                                        // reduce + pointwise
      int cell = (s * 32 + rl_r) * 16 + un_r;
      float g0 = bq0, g1 = bq1, g2 = bq2, g3 = bq3;
      #pragma unroll
      for (int sl = 0; sl < 4; ++sl) {
        const float* cp = Call + (size_t)(g * 4 + sl) * 8192 + cell * 4;
        union { unsigned long long q[2]; float f[4]; } uv;
        uv.q[0] = ld_u64(cp); uv.q[1] = ld_u64(cp + 2);
        g0 += uv.f[0]; g1 += uv.f[1]; g2 += uv.f[2]; g3 += uv.f[3];
      }
      creg = sigm(g1) * creg + sigm(g0) * tanhfa(g2);
      float h = sigm(g3) * tanhfa(creg);
      short hi, lo; split2(h, hi, lo);
      hsplit[un_r * 32 + rl_r] = ((unsigned)(unsigned short)hi << 16) | (unsigned short)lo;
    } else if (st + 2 < TS) {
      conv_x(x + (size_t)(st + 2) * 65536, xrH[(st + 2) & 3], xrL[(st + 2) & 3], b, t - 512);
    }
    __syncthreads();
    if (t < 64) {                                         // pack h (UC)
      int rl = t >> 1, seg = t & 1;
      int row = s * 32 + rl;
      int k0 = g * 16 + seg * 8;
      int kbg = k0 >> 5, kseg = (k0 >> 3) & 3;
      int lane_ = (kseg << 4) | (row & 15);
      int off = ((kbg * 8 + (row >> 4)) * 64 + lane_) * 8;
      unsigned long long h64[2] = {0, 0}, l64[2] = {0, 0};
      #pragma unroll
      for (int j = 0; j < 8; ++j) {
        unsigned v = hsplit[(seg * 8 + j) * 32 + rl];
        h64[j >> 2] |= (unsigned long long)(v >> 16) << ((j & 3) * 16);
        l64[j >> 2] |= (unsigned long long)(v & 0xFFFFu) << ((j & 3) * 16);
      }
      st_u64(hpH[wb] + off, h64[0]); st_u64(hpH[wb] + off + 4, h64[1]);
      st_u64(hpL[wb] + off, l64[0]); st_u64(hpL[wb] + off + 4, l64[1]);
    }
    setflag(&hflag[b], (unsigned)(st + 2));
  }

  // ================= switch to decoder =================
  load_gw(dWx, dWh, g, s, sBh, sBl);
  if (b >= 128) load_fcw(fcW, (b - 128) >> 5, (b - 128) & 31, sFh, sFl);
  if (t < 32) {                                           // zero y0 (slot 0)
    int off = (b * 32 + t) * 8;
    st_u64(xrH[0] + off, 0ull); st_u64(xrH[0] + off + 4, 0ull);
    st_u64(xrL[0] + off, 0ull); st_u64(xrL[0] + off + 4, 0ull);
  }
  creg = 0.0f;
  if (t < 512) {
    int ug = g * 16 + un_r;
    bq0 = db[0 * 1024 + ug]; bq1 = db[1 * 1024 + ug];
    bq2 = db[2 * 1024 + ug]; bq3 = db[3 * 1024 + ug];
  }
  float fcb_r = (t < 512) ? fcb[t] : 0.f;
  setflag(&hflag[b], (unsigned)(TS + 2));

  // ================= decoder =================
  const unsigned DB = (unsigned)(TS + 2);
  for (int st = 0; st < TS; ++st) {
    const int rb = st & 1, wb = rb ^ 1;
    f32x4 z = {0.f, 0.f, 0.f, 0.f};
    f32x4 acc[12] = {z, z, z, z, z, z, z, z, z, z, z, z};
    waitflags(hflag + s * 64, 64, DB + (unsigned)st, &sDead);
    if (sDead) return;
    gg_part<4>(hpH[rb], hpL[rb], sBh, sBl, mt, l, s * 8 + kh * 4, 4 + kh * 4, acc);
    waitflags(yflag, 128, (unsigned)st, &sDead);          // y(st-1)
    if (sDead) return;
    gg_part<2>(xrH[st & 1], xrL[st & 1], sBh, sBl, mt, l, s * 4 + kh * 2, kh * 2, acc);
    wait4(hflag + g * 4, DB + (unsigned)st, false, &sDead);
    if (sDead) return;
    {
      f32x4 sv[4];
      #pragma unroll
      for (int nt = 0; nt < 4; ++nt)
        sv[nt] = acc[nt * 3] + (acc[nt * 3 + 1] + acc[nt * 3 + 2]);
      if (kh == 1) {
        #pragma unroll
        for (int j = 0; j < 4; ++j) {
          int cell = (mt * 16 + ((l >> 4) << 2) + j) * 16 + (l & 15);
          float4 val = make_float4(sv[0][j], sv[1][j], sv[2][j], sv[3][j]);
          *(float4*)&cstage[cell * 4] = val;
        }
      }
      __syncthreads();
      if (kh == 0) {
        #pragma unroll
        for (int j = 0; j < 4; ++j) {
          int cell = (mt * 16 + ((l >> 4) << 2) + j) * 16 + (l & 15);
          float4 o = *(const float4*)&cstage[cell * 4];
          union { float f[4]; unsigned long long q[2]; } uv;
          uv.f[0] = sv[0][j] + o.x; uv.f[1] = sv[1][j] + o.y;
          uv.f[2] = sv[2][j] + o.z; uv.f[3] = sv[3][j] + o.w;
          st_u64(Cb + cell * 4, uv.q[0]);
          st_u64(Cb + cell * 4 + 2, uv.q[1]);
        }
      }
    }
    setflag(&pflag[b], (unsigned)(TS + st + 1));
    wait4(pflag + g * 4, (unsigned)(TS + st + 1), true, &sDead);  // + THE inv
    if (sDead) return;
    if (t < 512) {
      int cell = (s * 32 + rl_r) * 16 + un_r;
      float g0 = bq0, g1 = bq1, g2 = bq2, g3 = bq3;
      #pragma unroll
      for (int sl = 0; sl < 4; ++sl) {
        const float* cp = Call + (size_t)(g * 4 + sl) * 8192 + cell * 4;
        union { unsigned long long q[2]; float f[4]; } uv;
        uv.q[0] = ld_u64(cp); uv.q[1] = ld_u64(cp + 2);
        g0 += uv.f[0]; g1 += uv.f[1]; g2 += uv.f[2]; g3 += uv.f[3];
      }
      creg = sigm(g1) * creg + sigm(g0) * tanhfa(g2);
      float h = sigm(g3) * tanhfa(creg);
      short hi, lo; split2(h, hi, lo);
      hsplit[un_r * 32 + rl_r] = ((unsigned)(unsigned short)hi << 16) | (unsigned short)lo;
    }
    __syncthreads();
    if (t < 64) {
      int rl = t >> 1, seg = t & 1;
      int row = s * 32 + rl;
      int k0 = g * 16 + seg * 8;
      int kbg = k0 >> 5, kseg = (k0 >> 3) & 3;
      int lane_ = (kseg << 4) | (row & 15);
      int off = ((kbg * 8 + (row >> 4)) * 64 + lane_) * 8;
      unsigned long long h64[2] = {0, 0}, l64[2] = {0, 0};
      #pragma unroll
      for (int j = 0; j < 8; ++j) {
        unsigned v = hsplit[(seg * 8 + j) * 32 + rl];
        h64[j >> 2] |= (unsigned long long)(v >> 16) << ((j & 3) * 16);
        l64[j >> 2] |= (unsigned long long)(v & 0xFFFFu) << ((j & 3) * 16);
      }
      st_u64(hpH[wb] + off, h64[0]); st_u64(hpH[wb] + off + 4, h64[1]);
      st_u64(hpL[wb] + off, l64[0]); st_u64(hpL[wb] + off + 4, l64[1]);
    }
    setflag(&hflag[b], DB + (unsigned)(st + 1));

    if (b >= 128) {
      // ---- fc GEMM (UC hp reads; fence-free) ----
      const int f = b - 128, kg = f >> 5, cg = f & 31;
      waitflags(hflag + kg * 64, 64, DB + (unsigned)(st + 1), &sDead);
      if (sDead) return;
      {
        const bf16x8* FB = (const bf16x8*)sFh;
        const bf16x8* FL = (const bf16x8*)sFl;
        f32x4 a0 = z, a1 = z, a2 = z;
        #pragma unroll
        for (int kb = 0; kb < 4; ++kb) {
          int gkb = kg * 8 + kh * 4 + kb;
          bf16x8 ah = ld_frag(hpH[wb] + ((gkb * 8 + mt) * 64 + l) * 8);
          bf16x8 al = ld_frag(hpL[wb] + ((gkb * 8 + mt) * 64 + l) * 8);
          bf16x8 bh = FB[(kh * 4 + kb) * 64 + l];
          bf16x8 bl = FL[(kh * 4 + kb) * 64 + l];
          a0 = MFMA(ah, bh, a0, 0, 0, 0);
          a1 = MFMA(ah, bl, a1, 0, 0, 0);
          a2 = MFMA(al, bh, a2, 0, 0, 0);
        }
        f32x4 sv = a0 + (a1 + a2);
        int slice = kg * 2 + kh;
        int col = cg * 16 + (l & 15), r0 = mt * 16 + ((l >> 4) << 2);
        #pragma unroll
        for (int j = 0; j < 4; ++j)
          st_f32(&fp[(size_t)(slice * 128 + r0 + j) * 512 + col], sv[j]);
      }
      setflag(&fflag[f], (unsigned)(st + 1));
    } else {
      // ---- softmax + y-pack (UC fp reads) ----
      waitflags(fflag, 128, (unsigned)(st + 1), &sDead);
      if (sDead) return;
      float v = 0.f, e = 0.f, mx;
      if (t < 512) {
        v = fcb_r;
        #pragma unroll
        for (int s8 = 0; s8 < 8; ++s8)
          v += ld_f32(&fp[(size_t)(s8 * 128 + b) * 512 + t]);
        mx = v;
        #pragma unroll
        for (int o = 32; o > 0; o >>= 1) mx = fmaxf(mx, __shfl_xor(mx, o));
        if (l == 0) red[w] = mx;
      }
      __syncthreads();
      if (t < 512) {
        mx = red[0];
        #pragma unroll
        for (int i = 1; i < 8; ++i) mx = fmaxf(mx, red[i]);
        e = __expf(v - mx);
        float ss = e;
        #pragma unroll
        for (int o = 32; o > 0; o >>= 1) ss += __shfl_xor(ss, o);
        if (l == 0) red[8 + w] = ss;
      }
      __syncthreads();
      if (t < 512) {
        float ss = (red[8] + red[9]) + (red[10] + red[11])
                 + (red[12] + red[13]) + (red[14] + red[15]);
        float y = e / ss;
        out[((size_t)st * 128 + b) * 512 + t] = y;
        ybuf[t] = y;
      }
      __syncthreads();
      if (t < 64) {                                       // pack y row b
        int kb = t >> 2, seg = t & 3;
        int k = kb * 32 + seg * 8;
        int lane_ = (seg << 4) | (b & 15), mtt = b >> 4;
        int off = ((kb * 8 + mtt) * 64 + lane_) * 8;
        int yw = (st & 1) ^ 1;
        unsigned long long h64[2] = {0, 0}, l64[2] = {0, 0};
        #pragma unroll
        for (int j = 0; j < 8; ++j) {
          short hi, lo; split2(ybuf[k + j], hi, lo);
          h64[j >> 2] |= (unsigned long long)(unsigned short)hi << ((j & 3) * 16);
          l64[j >> 2] |= (unsigned long long)(unsigned short)lo << ((j & 3) * 16);
        }
        st_u64(xrH[yw] + off, h64[0]); st_u64(xrH[yw] + off + 4, h64[1]);
        st_u64(xrL[yw] + off, l64[0]); st_u64(xrL[yw] + off + 4, l64[1]);
      }
      setflag(&yflag[b], (unsigned)(st + 1));
    }
  }
}

extern "C" void kernel_launch(void* const* d_in, const int* in_sizes, int n_in,
                              void* d_out, int out_size, void* d_ws, size_t ws_size,
                              hipStream_t stream) {
  const float* x   = (const float*)d_in[0];
  const float* h0  = (const float*)d_in[1];
  const float* c0  = (const float*)d_in[2];
  const float* eWx = (const float*)d_in[3];
  const float* eWh = (const float*)d_in[4];
  const float* eb  = (const float*)d_in[5];
  const float* dWx = (const float*)d_in[6];
  const float* dWh = (const float*)d_in[7];
  const float* db  = (const float*)d_in[8];
  const float* fcW = (const float*)d_in[9];
  const float* fcb = (const float*)d_in[10];
  float* out = (float*)d_out;

  if (ws_size < (size_t)WS_TOTAL) {
    hipMemsetAsync(d_out, 0xFF, (size_t)out_size * sizeof(float), stream);
    return;
  }
  hipMemsetAsync(d_ws, 0, 4096, stream);   // flag arrays
  hipLaunchKernelGGL(lstm8, dim3(256), dim3(1024), 0, stream,
                     x, h0, c0, eWx, eWh, eb, dWx, dWh, db, fcW, fcb, out,
                     (char*)d_ws);
}

// Round 9
// 16654.974 us; speedup vs baseline: 2.1322x; 1.1017x over previous
//
#include <hip/hip_runtime.h>

// ---------------------------------------------------------------------------
// Persistent seq2seq LSTM, v9 = v6 structure + pipelined GEMM + hierarchical
// low-congestion flag sync. 256 blocks x 1024 threads (16 waves: mt=w&7,
// kh=w>>3). Block p owns 16 gate cols (4 units x 4 gates), full K=1536 ->
// gates complete in-block; c in registers; no cross-block partial exchange
// (K-split disproven 3x: R5 UC-everything, R7 wbl2, R8 UC-exchange).
// GEMM: gg_pipe with depth-4 batched A prefetch (8 loads in flight/wave,
// 128KB/CU) -> L2-BW-bound instead of latency-bound (R4/R6 had VGPR=64, ~2
// loads in flight). Sync: per-block UC flag stores (no RMW); blocks 0..7 /
// 8..11 / 12..15 aggregate h/y/f 32-flag ranges and publish single epoch
// lines; consumers poll ONE line with t0 -> ~30x less LLC poll traffic.
// One acquire fence (L1+L2 inv) per block per step at the h-wait.
// Decoder: fc on blocks 128..255 (UC hp reads), softmax+y on 0..127.
// ---------------------------------------------------------------------------

#define TS 384

typedef __attribute__((ext_vector_type(8))) short bf16x8;
typedef __attribute__((ext_vector_type(4))) float f32x4;

// ws layout
#define WS_XR 4096u                      // x ring: 4 slots x (hi 128KB + lo 128KB)
#define XR_SLOT 262144u
#define WS_HP (WS_XR + 4u*XR_SLOT)       // h planes: 2 bufs x (hi 256KB + lo 256KB)
#define HP_BUF 524288u
#define WS_FPN (WS_HP + 2u*HP_BUF)       // fc partials 8*128*512*4 = 2MB
#define WS_TOTAL (WS_FPN + 2097152u)

#define MFMA __builtin_amdgcn_mfma_f32_16x16x32_bf16

__device__ __forceinline__ unsigned short bf16r(float v) {
  unsigned u = __float_as_uint(v);
  u += 0x7FFFu + ((u >> 16) & 1u);
  return (unsigned short)(u >> 16);
}
__device__ __forceinline__ float bf2f(unsigned short h) {
  return __uint_as_float(((unsigned)h) << 16);
}
__device__ __forceinline__ void split2(float v, short& hi, short& lo) {
  unsigned short h = bf16r(v);
  float r = v - bf2f(h);
  hi = (short)h; lo = (short)bf16r(r);
}
__device__ __forceinline__ float sigm(float v)  { return 1.0f / (1.0f + __expf(-v)); }
__device__ __forceinline__ float tanhfa(float v){ return 1.0f - 2.0f / (__expf(2.0f*v) + 1.0f); }

__device__ __forceinline__ void st_u64(void* p, unsigned long long v) {
  __hip_atomic_store((unsigned long long*)p, v, __ATOMIC_RELAXED, __HIP_MEMORY_SCOPE_AGENT);
}
__device__ __forceinline__ unsigned long long ld_u64(const void* p) {
  return __hip_atomic_load((const unsigned long long*)p, __ATOMIC_RELAXED, __HIP_MEMORY_SCOPE_AGENT);
}
__device__ __forceinline__ void st_u32(unsigned* p, unsigned v) {
  __hip_atomic_store(p, v, __ATOMIC_RELAXED, __HIP_MEMORY_SCOPE_AGENT);
}
__device__ __forceinline__ void st_f32(float* p, float v) {
  __hip_atomic_store(p, v, __ATOMIC_RELAXED, __HIP_MEMORY_SCOPE_AGENT);
}
__device__ __forceinline__ float ld_f32(const float* p) {
  return __hip_atomic_load(p, __ATOMIC_RELAXED, __HIP_MEMORY_SCOPE_AGENT);
}
union FRAG { unsigned long long q[2]; bf16x8 v; };
__device__ __forceinline__ bf16x8 ld_frag(const short* base) {
  FRAG u;
  u.q[0] = ld_u64(base);
  u.q[1] = ld_u64(base + 4);
  return u.v;
}

// ---- sync primitives --------------------------------------------------------
// arrival: drain payload UC stores, one flag store (no RMW, no trailing wait)
__device__ __forceinline__ void setflag(unsigned* flag, unsigned val) {
  asm volatile("s_waitcnt vmcnt(0)" ::: "memory");
  __syncthreads();
  if (threadIdx.x == 0)
    __hip_atomic_store(flag, val, __ATOMIC_RELAXED, __HIP_MEMORY_SCOPE_AGENT);
}
// hierarchical wait: aggregator (aggIdx>=0) polls its 32-flag range with 8
// lanes then publishes pub[aggIdx]=target; everyone polls pub[0..nPub) (t0).
__device__ __forceinline__ void wait_hier(const unsigned* flags, unsigned* pub,
    int aggIdx, int nPub, unsigned target, bool fence, int* sDead) {
  const int t = threadIdx.x;
  if (aggIdx >= 0) {
    if (t < 8) {
      const unsigned long long* q = (const unsigned long long*)(flags + aggIdx * 32 + t * 4);
      unsigned spins = 0;
      for (;;) {
        unsigned long long q0 = ld_u64(q), q1 = ld_u64(q + 1);
        bool ok = ((unsigned)q0 >= target) && ((unsigned)(q0 >> 32) >= target)
               && ((unsigned)q1 >= target) && ((unsigned)(q1 >> 32) >= target);
        if (__all(ok)) break;
        __builtin_amdgcn_s_sleep(1);
        if (++spins > (1u << 19)) { if (t == 0) *sDead = 1; break; }
      }
    }
    if (t == 0) st_u32(&pub[aggIdx], target);
  }
  if (t == 0) {
    unsigned spins = 0;
    for (;;) {
      bool ok = true;
      #pragma unroll
      for (int i = 0; i < 4; ++i) {
        if (i * 2 < nPub) {
          unsigned long long q0 = ld_u64((const unsigned long long*)pub + i);
          if (!((unsigned)q0 >= target && (unsigned)(q0 >> 32) >= target)) ok = false;
        }
      }
      if (ok) break;
      __builtin_amdgcn_s_sleep(1);
      if (++spins > (1u << 19)) { *sDead = 1; break; }
    }
    if (fence) __builtin_amdgcn_fence(__ATOMIC_ACQUIRE, "agent");
  }
  __syncthreads();
}
// direct 64-flag wait (fc's kg-range), 16 lanes x 4 flags — low traffic
__device__ __forceinline__ void wait64(const unsigned* flags, unsigned target, int* sDead) {
  if (threadIdx.x < 16) {
    const unsigned long long* q = (const unsigned long long*)(flags + threadIdx.x * 4);
    unsigned spins = 0;
    for (;;) {
      unsigned long long q0 = ld_u64(q), q1 = ld_u64(q + 1);
      bool ok = ((unsigned)q0 >= target) && ((unsigned)(q0 >> 32) >= target)
             && ((unsigned)q1 >= target) && ((unsigned)(q1 >> 32) >= target);
      if (__all(ok)) break;
      __builtin_amdgcn_s_sleep(1);
      if (++spins > (1u << 19)) { if (threadIdx.x == 0) *sDead = 1; break; }
    }
  }
  __syncthreads();
}

// ---- weight loaders --------------------------------------------------------
__device__ void load_gate_weights(const float* __restrict__ Wx, const float* __restrict__ Wh,
                                  int p, short* sBh, short* sBl) {
  for (int idx = threadIdx.x; idx < 24576; idx += 1024) {
    int j = idx & 7, l = (idx >> 3) & 63, kb = idx >> 9;
    int k = kb * 32 + ((l >> 4) << 3) + j;
    int c = l & 15;
    int gcol = (c >> 2) * 1024 + p * 4 + (c & 3);
    float wv = (k < 512) ? Wx[(size_t)k * 4096 + gcol]
                         : Wh[(size_t)(k - 512) * 4096 + gcol];
    short hi, lo; split2(wv, hi, lo);
    sBh[idx] = hi; sBl[idx] = lo;
  }
}
__device__ void load_fc_weights(const float* __restrict__ fcW, int kg, int cg,
                                short* sFh, short* sFl) {
  for (int idx = threadIdx.x; idx < 4096; idx += 1024) {
    int j = idx & 7, l = (idx >> 3) & 63, kb = idx >> 9;
    int unit = kg * 256 + kb * 32 + ((l >> 4) << 3) + j;
    int col = cg * 16 + (l & 15);
    short hi, lo; split2(fcW[(size_t)unit * 512 + col], hi, lo);
    sFh[idx] = hi; sFl[idx] = lo;
  }
}

// ---- pipelined gate GEMM: depth-D batched A prefetch, 6 accs ---------------
template<int NKB, int D>
__device__ __forceinline__ void gg_pipe(const short* AH_, const short* AL_,
    const short* BH_, const short* BL_, int mt, int l,
    int kbA0, int kbB0, f32x4* acc)
{
  const bf16x8* AH = (const bf16x8*)AH_;
  const bf16x8* AL = (const bf16x8*)AL_;
  const bf16x8* BH = (const bf16x8*)BH_;
  const bf16x8* BL = (const bf16x8*)BL_;
  bf16x8 pah[D], pal[D];
  #pragma unroll
  for (int i = 0; i < D; ++i) {
    pah[i] = AH[((kbA0 + i) * 8 + mt) * 64 + l];
    pal[i] = AL[((kbA0 + i) * 8 + mt) * 64 + l];
  }
  #pragma unroll
  for (int i = 0; i < NKB; ++i) {
    bf16x8 ah = pah[i % D], al = pal[i % D];
    if (i + D < NKB) {
      pah[i % D] = AH[((kbA0 + i + D) * 8 + mt) * 64 + l];
      pal[i % D] = AL[((kbA0 + i + D) * 8 + mt) * 64 + l];
    }
    bf16x8 bh = BH[(kbB0 + i) * 64 + l];
    bf16x8 bl = BL[(kbB0 + i) * 64 + l];
    const int a = (i & 1) * 3;
    acc[a + 0] = MFMA(ah, bh, acc[a + 0], 0, 0, 0);
    acc[a + 1] = MFMA(ah, bl, acc[a + 1], 0, 0, 0);
    acc[a + 2] = MFMA(al, bh, acc[a + 2], 0, 0, 0);
  }
}
__device__ __forceinline__ void gg_finish(f32x4* acc, int kh, int mt, int l,
                                          float* LDSgate) {
  f32x4 s = (acc[0] + acc[3]) + ((acc[1] + acc[4]) + (acc[2] + acc[5]));
  const int col = l & 15, r0 = mt * 16 + ((l >> 4) << 2);
  float* plane = LDSgate + kh * 2176;
  #pragma unroll
  for (int j = 0; j < 4; ++j) plane[(r0 + j) * 17 + col] = s[j];
}

// ---- x conversion into fragment-ordered x-ring slot ------------------------
__device__ __forceinline__ void conv_x(const float* __restrict__ xsrc,
                                       short* dstH, short* dstL, int p, int tl) {
  if (tl < 32) {
    int g = p * 32 + tl;                      // 0..8191
    int l = g & 63, mt = (g >> 6) & 7, kb = g >> 9;
    int row = mt * 16 + (l & 15), k = kb * 32 + ((l >> 4) << 3);
    const float* xs = xsrc + (size_t)row * 512 + k;
    unsigned long long h64[2] = {0, 0}, l64[2] = {0, 0};
    #pragma unroll
    for (int j = 0; j < 8; ++j) {
      short hi, lo; split2(xs[j], hi, lo);
      h64[j >> 2] |= (unsigned long long)(unsigned short)hi << ((j & 3) * 16);
      l64[j >> 2] |= (unsigned long long)(unsigned short)lo << ((j & 3) * 16);
    }
    int off = g * 8;
    st_u64(dstH + off, h64[0]); st_u64(dstH + off + 4, h64[1]);
    st_u64(dstL + off, l64[0]); st_u64(dstL + off + 4, l64[1]);
  }
}

__global__ void __launch_bounds__(1024, 1)
lstm9(const float* __restrict__ x, const float* __restrict__ h0p,
      const float* __restrict__ c0p, const float* __restrict__ eWx,
      const float* __restrict__ eWh, const float* __restrict__ eb,
      const float* __restrict__ dWx, const float* __restrict__ dWh,
      const float* __restrict__ db, const float* __restrict__ fcW,
      const float* __restrict__ fcb, float* __restrict__ out,
      char* __restrict__ ws)
{
  __shared__ __align__(16) short sBh[24576], sBl[24576];   // 96 KB
  __shared__ __align__(16) short sFh[4096], sFl[4096];     // 16 KB
  __shared__ float LDSgate[2 * 2176];                      // 17.4 KB
  __shared__ unsigned hsplit[512];
  __shared__ float ybuf[512];
  __shared__ float red[16];
  __shared__ int sDead;

  const int p = blockIdx.x, t = threadIdx.x;
  const int w = t >> 6, l = t & 63;
  const int mt = w & 7, kh = w >> 3;
  if (t == 0) sDead = 0;

  unsigned* hflag = (unsigned*)ws;                 // 256 flags
  unsigned* yflag = (unsigned*)(ws + 1024);        // 128 flags
  unsigned* fflag = (unsigned*)(ws + 2048);        // 128 flags
  unsigned* hpub  = (unsigned*)(ws + 3072);        // 8 epochs (one line)
  unsigned* ypub  = (unsigned*)(ws + 3200);        // 4 epochs
  unsigned* fpub  = (unsigned*)(ws + 3328);        // 4 epochs

  const int hagg = (p < 8) ? p : -1;
  const int yagg = (p >= 8 && p < 12) ? p - 8 : -1;
  const int fagg = (p >= 12 && p < 16) ? p - 12 : -1;

  short* xrH[4]; short* xrL[4];
  #pragma unroll
  for (int s4 = 0; s4 < 4; ++s4) {
    xrH[s4] = (short*)(ws + WS_XR + s4 * XR_SLOT);
    xrL[s4] = (short*)(ws + WS_XR + s4 * XR_SLOT + 131072u);
  }
  short* hpH[2]; short* hpL[2];
  #pragma unroll
  for (int b2 = 0; b2 < 2; ++b2) {
    hpH[b2] = (short*)(ws + WS_HP + b2 * HP_BUF);
    hpL[b2] = (short*)(ws + WS_HP + b2 * HP_BUF + 262144u);
  }
  float* fp = (float*)(ws + WS_FPN);

  const int row_pw = t & 127, u_pw = (t >> 7) & 3;

  // ================= init =================
  load_gate_weights(eWx, eWh, p, sBh, sBl);
  conv_x(x, xrH[0], xrL[0], p, t);                       // x(0)
  conv_x(x + 65536, xrH[1], xrL[1], p, t);               // x(1)
  if (t < 64) {                                          // h0 -> hp[0]
    int hg = p * 64 + t;
    int ll = hg & 63, mtt = (hg >> 6) & 7, hk = hg >> 9;
    int row = mtt * 16 + (ll & 15), k = hk * 32 + ((ll >> 4) << 3);
    const float* hs = h0p + (size_t)row * 1024 + k;
    unsigned long long h64[2] = {0, 0}, l64[2] = {0, 0};
    #pragma unroll
    for (int j = 0; j < 8; ++j) {
      short hi, lo; split2(hs[j], hi, lo);
      h64[j >> 2] |= (unsigned long long)(unsigned short)hi << ((j & 3) * 16);
      l64[j >> 2] |= (unsigned long long)(unsigned short)lo << ((j & 3) * 16);
    }
    int off = hg * 8;
    st_u64(hpH[0] + off, h64[0]); st_u64(hpH[0] + off + 4, h64[1]);
    st_u64(hpL[0] + off, l64[0]); st_u64(hpL[0] + off + 4, l64[1]);
  }
  float creg = 0.f, bq0 = 0.f, bq1 = 0.f, bq2 = 0.f, bq3 = 0.f;
  if (t < 512) {
    creg = c0p[(size_t)row_pw * 1024 + p * 4 + u_pw];
    bq0 = eb[0 * 1024 + p * 4 + u_pw];
    bq1 = eb[1 * 1024 + p * 4 + u_pw];
    bq2 = eb[2 * 1024 + p * 4 + u_pw];
    bq3 = eb[3 * 1024 + p * 4 + u_pw];
  }
  setflag(&hflag[p], 1u);
  wait_hier(hflag, hpub, hagg, 8, 1u, true, &sDead);     // init barrier
  if (sDead) return;

  // ================= encoder =================
  // epochs: enc step st waits (st+1), stores (st+2)
  for (int st = 0; st < TS; ++st) {
    int rb = st & 1, wb = rb ^ 1, xs = st & 3;
    f32x4 z = {0.f, 0.f, 0.f, 0.f};
    f32x4 acc[6] = {z, z, z, z, z, z};
    // x-part BEFORE the wait (x(st) readiness implied by passed epochs)
    gg_pipe<8, 4>(xrH[xs], xrL[xs], sBh, sBl, mt, l, kh * 8, kh * 8, acc);
    wait_hier(hflag, hpub, hagg, 8, (unsigned)(st + 1), true, &sDead);  // one fence/step
    if (sDead) return;
    gg_pipe<16, 4>(hpH[rb], hpL[rb], sBh, sBl, mt, l, kh * 16, 16 + kh * 16, acc);
    gg_finish(acc, kh, mt, l, LDSgate);
    __syncthreads();
    if (t < 512) {
      float g0 = LDSgate[row_pw * 17 + 0  + u_pw] + LDSgate[2176 + row_pw * 17 + 0  + u_pw] + bq0;
      float g1 = LDSgate[row_pw * 17 + 4  + u_pw] + LDSgate[2176 + row_pw * 17 + 4  + u_pw] + bq1;
      float g2 = LDSgate[row_pw * 17 + 8  + u_pw] + LDSgate[2176 + row_pw * 17 + 8  + u_pw] + bq2;
      float g3 = LDSgate[row_pw * 17 + 12 + u_pw] + LDSgate[2176 + row_pw * 17 + 12 + u_pw] + bq3;
      creg = sigm(g1) * creg + sigm(g0) * tanhfa(g2);
      float h = sigm(g3) * tanhfa(creg);
      short hi, lo; split2(h, hi, lo);
      hsplit[u_pw * 128 + row_pw] = ((unsigned)(unsigned short)hi << 16) | (unsigned short)lo;
    } else if (st + 2 < TS) {
      conv_x(x + (size_t)(st + 2) * 65536, xrH[(st + 2) & 3], xrL[(st + 2) & 3], p, t - 512);
    }
    __syncthreads();
    if (t < 128) {                                       // pack h slice (4 units)
      int r = t;
      unsigned w0 = hsplit[r], w1 = hsplit[128 + r], w2 = hsplit[256 + r], w3 = hsplit[384 + r];
      unsigned long long hi64 = (unsigned long long)(w0 >> 16)
        | ((unsigned long long)(w1 >> 16) << 16)
        | ((unsigned long long)(w2 >> 16) << 32)
        | ((unsigned long long)(w3 >> 16) << 48);
      unsigned long long lo64 = (unsigned long long)(w0 & 0xFFFFu)
        | ((unsigned long long)(w1 & 0xFFFFu) << 16)
        | ((unsigned long long)(w2 & 0xFFFFu) << 32)
        | ((unsigned long long)(w3 & 0xFFFFu) << 48);
      int hk = p >> 3, mtt = r >> 4;
      int lane_ = (((p >> 1) & 3) << 4) | (r & 15);
      int off = ((hk * 8 + mtt) * 64 + lane_) * 8 + (p & 1) * 4;
      st_u64(hpH[wb] + off, hi64);
      st_u64(hpL[wb] + off, lo64);
    }
    setflag(&hflag[p], (unsigned)(st + 2));
  }

  // ================= switch to decoder =================
  load_gate_weights(dWx, dWh, p, sBh, sBl);
  if (p >= 128) load_fc_weights(fcW, (p - 128) >> 5, (p - 128) & 31, sFh, sFl);
  if (t < 32) {                                          // zero y0 (slot 0)
    int off = (p * 32 + t) * 8;
    st_u64(xrH[0] + off, 0ull); st_u64(xrH[0] + off + 4, 0ull);
    st_u64(xrL[0] + off, 0ull); st_u64(xrL[0] + off + 4, 0ull);
  }
  creg = 0.0f;
  if (t < 512) {
    bq0 = db[0 * 1024 + p * 4 + u_pw];
    bq1 = db[1 * 1024 + p * 4 + u_pw];
    bq2 = db[2 * 1024 + p * 4 + u_pw];
    bq3 = db[3 * 1024 + p * 4 + u_pw];
  }
  float fcb_r = (t < 512) ? fcb[t] : 0.f;
  setflag(&hflag[p], (unsigned)(TS + 2));

  // ================= decoder =================
  const unsigned DB = (unsigned)(TS + 2);
  for (int st = 0; st < TS; ++st) {
    int rb = st & 1, wb = rb ^ 1;
    int ys = st & 1, yw = ys ^ 1;
    f32x4 z = {0.f, 0.f, 0.f, 0.f};
    f32x4 acc[6] = {z, z, z, z, z, z};
    wait_hier(hflag, hpub, hagg, 8, DB + (unsigned)st, true, &sDead);   // one fence/step
    if (sDead) return;
    gg_pipe<16, 4>(hpH[rb], hpL[rb], sBh, sBl, mt, l, kh * 16, 16 + kh * 16, acc);
    wait_hier(yflag, ypub, yagg, 4, (unsigned)st, false, &sDead);       // y(st-1)
    if (sDead) return;
    gg_pipe<8, 4>(xrH[ys], xrL[ys], sBh, sBl, mt, l, kh * 8, kh * 8, acc);
    gg_finish(acc, kh, mt, l, LDSgate);
    __syncthreads();
    if (t < 512) {
      float g0 = LDSgate[row_pw * 17 + 0  + u_pw] + LDSgate[2176 + row_pw * 17 + 0  + u_pw] + bq0;
      float g1 = LDSgate[row_pw * 17 + 4  + u_pw] + LDSgate[2176 + row_pw * 17 + 4  + u_pw] + bq1;
      float g2 = LDSgate[row_pw * 17 + 8  + u_pw] + LDSgate[2176 + row_pw * 17 + 8  + u_pw] + bq2;
      float g3 = LDSgate[row_pw * 17 + 12 + u_pw] + LDSgate[2176 + row_pw * 17 + 12 + u_pw] + bq3;
      creg = sigm(g1) * creg + sigm(g0) * tanhfa(g2);
      float h = sigm(g3) * tanhfa(creg);
      short hi, lo; split2(h, hi, lo);
      hsplit[u_pw * 128 + row_pw] = ((unsigned)(unsigned short)hi << 16) | (unsigned short)lo;
    }
    __syncthreads();
    if (t < 128) {
      int r = t;
      unsigned w0 = hsplit[r], w1 = hsplit[128 + r], w2 = hsplit[256 + r], w3 = hsplit[384 + r];
      unsigned long long hi64 = (unsigned long long)(w0 >> 16)
        | ((unsigned long long)(w1 >> 16) << 16)
        | ((unsigned long long)(w2 >> 16) << 32)
        | ((unsigned long long)(w3 >> 16) << 48);
      unsigned long long lo64 = (unsigned long long)(w0 & 0xFFFFu)
        | ((unsigned long long)(w1 & 0xFFFFu) << 16)
        | ((unsigned long long)(w2 & 0xFFFFu) << 32)
        | ((unsigned long long)(w3 & 0xFFFFu) << 48);
      int hk = p >> 3, mtt = r >> 4;
      int lane_ = (((p >> 1) & 3) << 4) | (r & 15);
      int off = ((hk * 8 + mtt) * 64 + lane_) * 8 + (p & 1) * 4;
      st_u64(hpH[wb] + off, hi64);
      st_u64(hpL[wb] + off, lo64);
    }
    setflag(&hflag[p], DB + (unsigned)(st + 1));          // h(st) ready

    if (p >= 128) {
      // ---- fc GEMM on blocks 128..255 (UC hp reads, preloaded) ----
      const int f = p - 128, kg = f >> 5, cg = f & 31;
      wait64(hflag + kg * 64, DB + (unsigned)(st + 1), &sDead);
      if (sDead) return;
      {
        const bf16x8* FB = (const bf16x8*)sFh;
        const bf16x8* FL = (const bf16x8*)sFl;
        bf16x8 fah[4], fal[4];
        #pragma unroll
        for (int kb = 0; kb < 4; ++kb) {
          int gkb = kg * 8 + kh * 4 + kb;
          fah[kb] = ld_frag(hpH[wb] + ((gkb * 8 + mt) * 64 + l) * 8);
          fal[kb] = ld_frag(hpL[wb] + ((gkb * 8 + mt) * 64 + l) * 8);
        }
        f32x4 a0 = z, a1 = z, a2 = z;
        #pragma unroll
        for (int kb = 0; kb < 4; ++kb) {
          bf16x8 bh = FB[(kh * 4 + kb) * 64 + l];
          bf16x8 bl = FL[(kh * 4 + kb) * 64 + l];
          a0 = MFMA(fah[kb], bh, a0, 0, 0, 0);
          a1 = MFMA(fah[kb], bl, a1, 0, 0, 0);
          a2 = MFMA(fal[kb], bh, a2, 0, 0, 0);
        }
        f32x4 s = a0 + (a1 + a2);
        int slice = kg * 2 + kh;
        int col = cg * 16 + (l & 15), r0 = mt * 16 + ((l >> 4) << 2);
        #pragma unroll
        for (int j = 0; j < 4; ++j)
          st_f32(&fp[(size_t)(slice * 128 + r0 + j) * 512 + col], s[j]);
      }
      setflag(&fflag[f], (unsigned)(st + 1));
    } else {
      // ---- softmax + y-pack on blocks 0..127 (UC fp reads, preloaded) ----
      wait_hier(fflag, fpub, fagg, 4, (unsigned)(st + 1), false, &sDead);
      if (sDead) return;
      float v = 0.f, e = 0.f, mx;
      if (t < 512) {
        float tv[8];
        #pragma unroll
        for (int s8 = 0; s8 < 8; ++s8)
          tv[s8] = ld_f32(&fp[(size_t)(s8 * 128 + p) * 512 + t]);
        v = fcb_r + ((tv[0] + tv[1]) + (tv[2] + tv[3]))
                  + ((tv[4] + tv[5]) + (tv[6] + tv[7]));
        mx = v;
        #pragma unroll
        for (int o = 32; o > 0; o >>= 1) mx = fmaxf(mx, __shfl_xor(mx, o));
        if (l == 0) red[w] = mx;
      }
      __syncthreads();
      if (t < 512) {
        mx = red[0];
        #pragma unroll
        for (int i = 1; i < 8; ++i) mx = fmaxf(mx, red[i]);
        e = __expf(v - mx);
        float ss = e;
        #pragma unroll
        for (int o = 32; o > 0; o >>= 1) ss += __shfl_xor(ss, o);
        if (l == 0) red[8 + w] = ss;
      }
      __syncthreads();
      if (t < 512) {
        float ss = (red[8] + red[9]) + (red[10] + red[11])
                 + (red[12] + red[13]) + (red[14] + red[15]);
        float y = e / ss;
        out[((size_t)st * 128 + p) * 512 + t] = y;
        ybuf[t] = y;
      }
      __syncthreads();
      if (t < 64) {                                      // pack y row p
        int kb = t >> 2, seg = t & 3;
        int k = kb * 32 + seg * 8;
        int lane_ = (seg << 4) | (p & 15), mtt = p >> 4;
        int off = ((kb * 8 + mtt) * 64 + lane_) * 8;
        unsigned long long h64[2] = {0, 0}, l64[2] = {0, 0};
        #pragma unroll
        for (int j = 0; j < 8; ++j) {
          short hi, lo; split2(ybuf[k + j], hi, lo);
          h64[j >> 2] |= (unsigned long long)(unsigned short)hi << ((j & 3) * 16);
          l64[j >> 2] |= (unsigned long long)(unsigned short)lo << ((j & 3) * 16);
        }
        st_u64(xrH[yw] + off, h64[0]); st_u64(xrH[yw] + off + 4, h64[1]);
        st_u64(xrL[yw] + off, l64[0]); st_u64(xrL[yw] + off + 4, l64[1]);
      }
      setflag(&yflag[p], (unsigned)(st + 1));
    }
  }
}

extern "C" void kernel_launch(void* const* d_in, const int* in_sizes, int n_in,
                              void* d_out, int out_size, void* d_ws, size_t ws_size,
                              hipStream_t stream) {
  const float* x   = (const float*)d_in[0];
  const float* h0  = (const float*)d_in[1];
  const float* c0  = (const float*)d_in[2];
  const float* eWx = (const float*)d_in[3];
  const float* eWh = (const float*)d_in[4];
  const float* eb  = (const float*)d_in[5];
  const float* dWx = (const float*)d_in[6];
  const float* dWh = (const float*)d_in[7];
  const float* db  = (const float*)d_in[8];
  const float* fcW = (const float*)d_in[9];
  const float* fcb = (const float*)d_in[10];
  float* out = (float*)d_out;

  if (ws_size < (size_t)WS_TOTAL) {
    hipMemsetAsync(d_out, 0xFF, (size_t)out_size * sizeof(float), stream);
    return;
  }
  hipMemsetAsync(d_ws, 0, 4096, stream);   // flags + pubs
  hipLaunchKernelGGL(lstm9, dim3(256), dim3(1024), 0, stream,
                     x, h0, c0, eWx, eWh, eb, dWx, dWh, db, fcW, fcb, out,
                     (char*)d_ws);
}